// Round 4
// baseline (293.967 us; speedup 1.0000x reference)
//
#include <hip/hip_runtime.h>
#include <hip/hip_bf16.h>
#include <stdint.h>

// minGRU: proj = x@W_f^T + b_f (bf16 GEMM) -> chunked linear scan -> out = h@W_down^T
// B=4 T=4096 D=1024 E=1536.
// GEMMs: 256x256 tile, BK=32, 8 waves, 4-deep LDS ring, counted vmcnt(8),
// ONE barrier per K-tile (LDS/MFMA pipe overlap via compiler lgkmcnt),
// T2 XOR swizzle, operand-swapped MFMA epilogue, XCD supertile mapping.

typedef __bf16 bf16x8 __attribute__((ext_vector_type(8)));
typedef float  f32x4  __attribute__((ext_vector_type(4)));

__device__ __forceinline__ uint16_t f32_to_bf16(float f) {
  union { float f; uint32_t u; } v; v.f = f;
  uint32_t r = (v.u + 0x7FFFu + ((v.u >> 16) & 1u)) >> 16;  // RNE
  return (uint16_t)r;
}
__device__ __forceinline__ float bf16_to_f32(uint16_t u) {
  union { uint32_t u; float f; } v; v.u = ((uint32_t)u) << 16;
  return v.f;
}

__device__ __forceinline__ void gload_lds16(const uint16_t* g, uint16_t* l) {
  __builtin_amdgcn_global_load_lds(
      (__attribute__((address_space(1))) void*)(g),
      (__attribute__((address_space(3))) void*)(l), 16, 0, 0);
}

// ---------------- cast fp32 -> bf16, x4 vectorized ----------------
__global__ __launch_bounds__(256) void cast_f32_bf16(
    const float* __restrict__ in, uint16_t* __restrict__ out, int n4) {
  int i = blockIdx.x * blockDim.x + threadIdx.x;
  if (i >= n4) return;
  float4 v = reinterpret_cast<const float4*>(in)[i];
  ushort4 o;
  o.x = f32_to_bf16(v.x); o.y = f32_to_bf16(v.y);
  o.z = f32_to_bf16(v.z); o.w = f32_to_bf16(v.w);
  reinterpret_cast<ushort4*>(out)[i] = o;
}

// ---------------- bf16 GEMM, C = A(M,K) * Bt(N,K)^T, 256^2 pipelined --------
// LDS ring: 4 bufs x 16KB. K-tile u lives in buf[u&3].
// Per iter u: fence{vmcnt(8); s_barrier} then ONE basic block:
//   rd A0-3,B0-3 (8x b128); stage tile u+3 (4x gload_lds);
//   [sched_barrier] 16 MFMA (m0-3 x n0-3); rd A4-7; [sched_barrier]
//   16 MFMA (m4-7 x n0-3).
// Compiler emits counted lgkmcnt for read->MFMA deps => LDS pipe overlaps
// MFMA pipe within and across waves (waves drift freely between fences).
// WAR: stage targets buf[(u-1)&3]; every wave's reads of it completed before
// this iter's fence barrier (block-2 MFMA issue requires lgkmcnt drain).
// RAW: vmcnt(8) leaves tiles u+1,u+2 (8 loads) in flight; tile u landed.
template <int OUT_BF16_BIAS>
__global__ __launch_bounds__(512, 2) void gemm256(
    const uint16_t* __restrict__ A, const uint16_t* __restrict__ Bt,
    const float* __restrict__ bias, void* __restrict__ Cout,
    int M, int N, int K) {
  __shared__ alignas(16) uint16_t lds[4 * 16384];  // 128 KB

  const int tid  = threadIdx.x;
  const int wave = tid >> 6;
  const int lane = tid & 63;
  const int wr = wave >> 2;      // 0..1  (rows, 128 each)
  const int wc = wave & 3;       // 0..3  (cols, 64 each)

  // XCD supertile map: XCD x (= bid&7 round-robin) owns m-tiles [8x,8x+8)
  const int l  = (int)blockIdx.x >> 3;
  const int x  = (int)blockIdx.x & 7;
  const int m0 = (x * 8 + (l & 7)) << 8;
  const int n0 = (l >> 3) << 8;

  const int NT = K >> 5;  // BK = 32

  // staging: linear LDS dest, inverse-swizzled global source
  const int srow = wave * 16 + (lane >> 2);
  const int skg  = (lane & 3) ^ ((lane >> 3) & 3);
  const uint16_t* Ag0 = A  + (size_t)(m0 + srow) * K + skg * 8;
  const uint16_t* Ag1 = A  + (size_t)(m0 + 128 + srow) * K + skg * 8;
  const uint16_t* Bg0 = Bt + (size_t)(n0 + srow) * K + skg * 8;
  const uint16_t* Bg1 = Bt + (size_t)(n0 + 128 + srow) * K + skg * 8;
  const int sdw = wave * 512;  // elems

  // swizzled read bases (elems): row*32 + (kg ^ ((row>>1)&3))*8
  const int kgq = (lane >> 4) ^ ((lane >> 1) & 3);
  const int rA = (wr * 128 + (lane & 15)) * 32 + kgq * 8;
  const int rB = (wc * 64  + (lane & 15)) * 32 + kgq * 8;

  f32x4 acc[8][4] = {};

  // prologue: stage tiles 0,1,2
#pragma unroll
  for (int tt = 0; tt < 3; ++tt) {
    uint16_t* sb = &lds[tt * 16384];
    gload_lds16(Ag0 + tt * 32, sb + sdw);
    gload_lds16(Ag1 + tt * 32, sb + 4096 + sdw);
    gload_lds16(Bg0 + tt * 32, sb + 8192 + sdw);
    gload_lds16(Bg1 + tt * 32, sb + 12288 + sdw);
  }

  for (int u = 0; u < NT; ++u) {
    const uint16_t* Ab = &lds[(u & 3) * 16384 + rA];
    const uint16_t* Bb = &lds[(u & 3) * 16384 + 8192 + rB];
    const int us = (u + 3 < NT) ? (u + 3) : (NT - 1);  // clamp: uniform vmcnt
    uint16_t* sb = &lds[((u + 3) & 3) * 16384];
    const size_t kofs = (size_t)us * 32;

    asm volatile("s_waitcnt vmcnt(8)" ::: "memory");
    __builtin_amdgcn_s_barrier();

    bf16x8 af0[4], af1[4], bfr[4];
    // block-1 operand reads (8x ds_read_b128)
#pragma unroll
    for (int m = 0; m < 4; ++m) af0[m] = *reinterpret_cast<const bf16x8*>(Ab + m * 512);
#pragma unroll
    for (int n = 0; n < 4; ++n) bfr[n] = *reinterpret_cast<const bf16x8*>(Bb + n * 512);
    // stage tile u+3 into buf[(u-1)&3]
    gload_lds16(Ag0 + kofs, sb + sdw);
    gload_lds16(Ag1 + kofs, sb + 4096 + sdw);
    gload_lds16(Bg0 + kofs, sb + 8192 + sdw);
    gload_lds16(Bg1 + kofs, sb + 12288 + sdw);
    __builtin_amdgcn_sched_barrier(0);
    __builtin_amdgcn_s_setprio(1);
#pragma unroll
    for (int m = 0; m < 4; ++m)
#pragma unroll
      for (int n = 0; n < 4; ++n)
        acc[m][n] = __builtin_amdgcn_mfma_f32_16x16x32_bf16(bfr[n], af0[m], acc[m][n], 0, 0, 0);
    __builtin_amdgcn_s_setprio(0);
    // block-2 A reads drain under other waves' / block-1 MFMA
#pragma unroll
    for (int m = 0; m < 4; ++m) af1[m] = *reinterpret_cast<const bf16x8*>(Ab + (m + 4) * 512);
    __builtin_amdgcn_sched_barrier(0);
    __builtin_amdgcn_s_setprio(1);
#pragma unroll
    for (int m = 0; m < 4; ++m)
#pragma unroll
      for (int n = 0; n < 4; ++n)
        acc[m + 4][n] = __builtin_amdgcn_mfma_f32_16x16x32_bf16(bfr[n], af1[m], acc[m + 4][n], 0, 0, 0);
    __builtin_amdgcn_s_setprio(0);
    __builtin_amdgcn_sched_barrier(0);
  }
  asm volatile("s_waitcnt vmcnt(0)" ::: "memory");

  // ---- epilogue (operand-swapped layout):
  //   row = m0 + wr*128 + m*16 + (lane&15)
  //   col = n0 + wc*64 + n*16 + (lane>>4)*4 + i
  const int r0 = m0 + wr * 128 + (lane & 15);
  const int cb = n0 + wc * 64 + (lane >> 4) * 4;
  if constexpr (OUT_BF16_BIAS) {
    uint16_t* C = (uint16_t*)Cout;
#pragma unroll
    for (int n = 0; n < 4; ++n) {
      const int col = cb + n * 16;
      const float4 bv = *reinterpret_cast<const float4*>(&bias[col]);
#pragma unroll
      for (int m = 0; m < 8; ++m) {
        const int row = r0 + m * 16;
        ushort4 o;
        o.x = f32_to_bf16(acc[m][n][0] + bv.x);
        o.y = f32_to_bf16(acc[m][n][1] + bv.y);
        o.z = f32_to_bf16(acc[m][n][2] + bv.z);
        o.w = f32_to_bf16(acc[m][n][3] + bv.w);
        *reinterpret_cast<ushort4*>(&C[(size_t)row * N + col]) = o;
      }
    }
  } else {
    float* C = (float*)Cout;
#pragma unroll
    for (int n = 0; n < 4; ++n) {
      const int col = cb + n * 16;
#pragma unroll
      for (int m = 0; m < 8; ++m) {
        const int row = r0 + m * 16;
        float4 o;
        o.x = acc[m][n][0]; o.y = acc[m][n][1];
        o.z = acc[m][n][2]; o.w = acc[m][n][3];
        *reinterpret_cast<float4*>(&C[(size_t)row * N + col]) = o;
      }
    }
  }
}

// ---------------- scan: h_t = a_t*h_{t-1} + v_t,  h_0 = 0.5 ----------------
__device__ __forceinline__ void gate_val(float kz, float hx, float& a, float& v) {
  float ek = __expf(-fabsf(kz));
  float r  = 1.0f / (1.0f + ek);
  float z  = (kz >= 0.0f) ? r : ek * r;   // sigmoid(k)
  a        = (kz >= 0.0f) ? ek * r : r;   // 1 - sigmoid(k)
  float g;
  if (hx >= 0.0f) {
    g = hx + 0.5f;
  } else {
    float eh = __expf(hx);
    g = eh / (1.0f + eh);
  }
  v = z * g;
}

__global__ __launch_bounds__(256) void scan_pass1(
    const uint16_t* __restrict__ proj, float* __restrict__ Ac,
    float* __restrict__ Vc, int T, int E, int CH, int L) {
  const int e = blockIdx.x * 256 + threadIdx.x;
  const int c = blockIdx.y;
  const int b = blockIdx.z;
  const int N1 = 2 * E;
  const uint16_t* p = proj + (size_t)(b * T + c * L) * N1 + e;
  float A = 1.0f, V = 0.0f;
  for (int t = 0; t < L; ++t) {
    float kz = bf16_to_f32(p[0]);
    float hx = bf16_to_f32(p[E]);
    float a, v; gate_val(kz, hx, a, v);
    A *= a;
    V = a * V + v;
    p += N1;
  }
  const size_t idx = ((size_t)(b * CH + c)) * E + e;
  Ac[idx] = A; Vc[idx] = V;
}

__global__ __launch_bounds__(256) void scan_pass2(
    const float* __restrict__ Ac, const float* __restrict__ Vc,
    float* __restrict__ hstart, int E, int CH) {
  const int e = blockIdx.x * 256 + threadIdx.x;
  const int b = blockIdx.y;
  float h = 0.5f;
  for (int c = 0; c < CH; ++c) {
    const size_t idx = ((size_t)(b * CH + c)) * E + e;
    hstart[idx] = h;
    h = Ac[idx] * h + Vc[idx];
  }
}

__global__ __launch_bounds__(256) void scan_pass3(
    const uint16_t* __restrict__ proj, const float* __restrict__ hstart,
    uint16_t* __restrict__ hout, int T, int E, int CH, int L) {
  const int e = blockIdx.x * 256 + threadIdx.x;
  const int c = blockIdx.y;
  const int b = blockIdx.z;
  const int N1 = 2 * E;
  const uint16_t* p = proj + (size_t)(b * T + c * L) * N1 + e;
  uint16_t* o = hout + (size_t)(b * T + c * L) * E + e;
  float h = hstart[((size_t)(b * CH + c)) * E + e];
  for (int t = 0; t < L; ++t) {
    float kz = bf16_to_f32(p[0]);
    float hx = bf16_to_f32(p[E]);
    float a, v; gate_val(kz, hx, a, v);
    h = a * h + v;
    *o = f32_to_bf16(h);
    p += N1; o += E;
  }
}

extern "C" void kernel_launch(void* const* d_in, const int* in_sizes, int n_in,
                              void* d_out, int out_size, void* d_ws, size_t ws_size,
                              hipStream_t stream) {
  const float* x   = (const float*)d_in[0];
  const float* W_f = (const float*)d_in[1];
  const float* b_f = (const float*)d_in[2];
  const float* W_d = (const float*)d_in[3];
  const int Bb = 4, T = 4096, D = 1024, E = 1536;
  const int M = Bb * T;        // 16384
  const int N1 = 2 * E;        // 3072
  const int CH = 64, L = T / CH;

  char* w = (char*)d_ws;
  uint16_t* x_bf  = (uint16_t*)w; w += (size_t)M * D * 2;
  uint16_t* Wf_bf = (uint16_t*)w; w += (size_t)N1 * D * 2;
  uint16_t* Wd_bf = (uint16_t*)w; w += (size_t)D * E * 2;
  uint16_t* proj  = (uint16_t*)w; w += (size_t)M * N1 * 2;
  uint16_t* h_bf  = (uint16_t*)w; w += (size_t)M * E * 2;
  float* Ac     = (float*)w; w += (size_t)Bb * CH * E * 4;
  float* Vc     = (float*)w; w += (size_t)Bb * CH * E * 4;
  float* hstart = (float*)w; w += (size_t)Bb * CH * E * 4;

  cast_f32_bf16<<<M * D / 4 / 256, 256, 0, stream>>>(x, x_bf, M * D / 4);
  cast_f32_bf16<<<N1 * D / 4 / 256, 256, 0, stream>>>(W_f, Wf_bf, N1 * D / 4);
  cast_f32_bf16<<<D * E / 4 / 256, 256, 0, stream>>>(W_d, Wd_bf, D * E / 4);

  // proj = x @ W_f^T + b_f (bf16 out);  grid 768 (= 64 m-tiles x 12 n-tiles)
  gemm256<1><<<(M / 256) * (N1 / 256), 512, 0, stream>>>(
      x_bf, Wf_bf, b_f, proj, M, N1, D);

  scan_pass1<<<dim3(E / 256, CH, Bb), 256, 0, stream>>>(proj, Ac, Vc, T, E, CH, L);
  scan_pass2<<<dim3(E / 256, Bb), 256, 0, stream>>>(Ac, Vc, hstart, E, CH);
  scan_pass3<<<dim3(E / 256, CH, Bb), 256, 0, stream>>>(proj, hstart, h_bf, T, E, CH, L);

  // out = h @ W_down^T (fp32 out);  grid 256 (= 64 m-tiles x 4 n-tiles)
  gemm256<0><<<(M / 256) * (D / 256), 512, 0, stream>>>(
      h_bf, Wd_bf, nullptr, d_out, M, D, E);
}

// Round 5
// 284.845 us; speedup vs baseline: 1.0320x; 1.0320x over previous
//
#include <hip/hip_runtime.h>
#include <hip/hip_bf16.h>
#include <stdint.h>

// minGRU: proj = x@W_f^T + b_f (bf16 GEMM) -> chunked linear scan -> out = h@W_down^T
// B=4 T=4096 D=1024 E=1536.
// GEMMs: 256x256 tile, BK=32, 8 waves, 4-deep LDS ring, counted vmcnt(8),
// one barrier per K-tile, T2 XOR swizzle, operand-swapped MFMA epilogue.
// R5: L2-fitting 2m x 4n patch block-mapping (per-XCD working set 3MB < 4MB L2).

typedef __bf16 bf16x8 __attribute__((ext_vector_type(8)));
typedef float  f32x4  __attribute__((ext_vector_type(4)));

__device__ __forceinline__ uint16_t f32_to_bf16(float f) {
  union { float f; uint32_t u; } v; v.f = f;
  uint32_t r = (v.u + 0x7FFFu + ((v.u >> 16) & 1u)) >> 16;  // RNE
  return (uint16_t)r;
}
__device__ __forceinline__ float bf16_to_f32(uint16_t u) {
  union { uint32_t u; float f; } v; v.u = ((uint32_t)u) << 16;
  return v.f;
}

__device__ __forceinline__ void gload_lds16(const uint16_t* g, uint16_t* l) {
  __builtin_amdgcn_global_load_lds(
      (__attribute__((address_space(1))) void*)(g),
      (__attribute__((address_space(3))) void*)(l), 16, 0, 0);
}

// ---------------- cast fp32 -> bf16, x4 vectorized ----------------
__global__ __launch_bounds__(256) void cast_f32_bf16(
    const float* __restrict__ in, uint16_t* __restrict__ out, int n4) {
  int i = blockIdx.x * blockDim.x + threadIdx.x;
  if (i >= n4) return;
  float4 v = reinterpret_cast<const float4*>(in)[i];
  ushort4 o;
  o.x = f32_to_bf16(v.x); o.y = f32_to_bf16(v.y);
  o.z = f32_to_bf16(v.z); o.w = f32_to_bf16(v.w);
  reinterpret_cast<ushort4*>(out)[i] = o;
}

// ---------------- bf16 GEMM, C = A(M,K) * Bt(N,K)^T, 256^2 pipelined --------
// Requires M == 16384 (64 m-tiles) and N % 1024 == 0 (n-tiles mult of 4).
// Block map: XCD x = bid&7 (round-robin dispatch). Patch = 2m x 4n tiles
// (A 1MB + B 2MB panels -> fits 4MB per-XCD L2). XCD x owns patches
// pi = x + 8k; within patch q = local&7 -> (dm=q>>2, dn=q&3).
template <int OUT_BF16_BIAS>
__global__ __launch_bounds__(512, 2) void gemm256(
    const uint16_t* __restrict__ A, const uint16_t* __restrict__ Bt,
    const float* __restrict__ bias, void* __restrict__ Cout,
    int M, int N, int K) {
  __shared__ alignas(16) uint16_t lds[4 * 16384];  // 128 KB

  const int tid  = threadIdx.x;
  const int wave = tid >> 6;
  const int lane = tid & 63;
  const int wr = wave >> 2;      // 0..1  (rows, 128 each)
  const int wc = wave & 3;       // 0..3  (cols, 64 each)

  // L2-fitting patch map (Mt = 64 m-tiles fixed; pm = pi&31, pn = pi>>5)
  const int bid = (int)blockIdx.x;
  const int xq  = bid & 7;
  const int j   = bid >> 3;
  const int pi  = xq + ((j >> 3) << 3);
  const int q   = j & 7;
  const int mt  = ((pi & 31) << 1) + (q >> 2);
  const int nt  = ((pi >> 5) << 2) + (q & 3);
  const int m0  = mt << 8;
  const int n0  = nt << 8;

  const int NT = K >> 5;  // BK = 32

  // staging: linear LDS dest, inverse-swizzled global source
  const int srow = wave * 16 + (lane >> 2);
  const int skg  = (lane & 3) ^ ((lane >> 3) & 3);
  const uint16_t* Ag0 = A  + (size_t)(m0 + srow) * K + skg * 8;
  const uint16_t* Ag1 = A  + (size_t)(m0 + 128 + srow) * K + skg * 8;
  const uint16_t* Bg0 = Bt + (size_t)(n0 + srow) * K + skg * 8;
  const uint16_t* Bg1 = Bt + (size_t)(n0 + 128 + srow) * K + skg * 8;
  const int sdw = wave * 512;  // elems

  // swizzled read bases (elems): row*32 + (kg ^ ((row>>1)&3))*8
  const int kgq = (lane >> 4) ^ ((lane >> 1) & 3);
  const int rA = (wr * 128 + (lane & 15)) * 32 + kgq * 8;
  const int rB = (wc * 64  + (lane & 15)) * 32 + kgq * 8;

  f32x4 acc[8][4] = {};

  // prologue: stage tiles 0,1,2
#pragma unroll
  for (int tt = 0; tt < 3; ++tt) {
    uint16_t* sb = &lds[tt * 16384];
    gload_lds16(Ag0 + tt * 32, sb + sdw);
    gload_lds16(Ag1 + tt * 32, sb + 4096 + sdw);
    gload_lds16(Bg0 + tt * 32, sb + 8192 + sdw);
    gload_lds16(Bg1 + tt * 32, sb + 12288 + sdw);
  }

  for (int u = 0; u < NT; ++u) {
    const uint16_t* Ab = &lds[(u & 3) * 16384 + rA];
    const uint16_t* Bb = &lds[(u & 3) * 16384 + 8192 + rB];
    const int us = (u + 3 < NT) ? (u + 3) : (NT - 1);  // clamp: uniform vmcnt
    uint16_t* sb = &lds[((u + 3) & 3) * 16384];
    const size_t kofs = (size_t)us * 32;

    asm volatile("s_waitcnt vmcnt(8)" ::: "memory");
    __builtin_amdgcn_s_barrier();

    bf16x8 af0[4], af1[4], bfr[4];
#pragma unroll
    for (int m = 0; m < 4; ++m) af0[m] = *reinterpret_cast<const bf16x8*>(Ab + m * 512);
#pragma unroll
    for (int n = 0; n < 4; ++n) bfr[n] = *reinterpret_cast<const bf16x8*>(Bb + n * 512);
    gload_lds16(Ag0 + kofs, sb + sdw);
    gload_lds16(Ag1 + kofs, sb + 4096 + sdw);
    gload_lds16(Bg0 + kofs, sb + 8192 + sdw);
    gload_lds16(Bg1 + kofs, sb + 12288 + sdw);
    __builtin_amdgcn_sched_barrier(0);
    __builtin_amdgcn_s_setprio(1);
#pragma unroll
    for (int m = 0; m < 4; ++m)
#pragma unroll
      for (int n = 0; n < 4; ++n)
        acc[m][n] = __builtin_amdgcn_mfma_f32_16x16x32_bf16(bfr[n], af0[m], acc[m][n], 0, 0, 0);
    __builtin_amdgcn_s_setprio(0);
#pragma unroll
    for (int m = 0; m < 4; ++m) af1[m] = *reinterpret_cast<const bf16x8*>(Ab + (m + 4) * 512);
    __builtin_amdgcn_sched_barrier(0);
    __builtin_amdgcn_s_setprio(1);
#pragma unroll
    for (int m = 0; m < 4; ++m)
#pragma unroll
      for (int n = 0; n < 4; ++n)
        acc[m + 4][n] = __builtin_amdgcn_mfma_f32_16x16x32_bf16(bfr[n], af1[m], acc[m + 4][n], 0, 0, 0);
    __builtin_amdgcn_s_setprio(0);
    __builtin_amdgcn_sched_barrier(0);
  }
  asm volatile("s_waitcnt vmcnt(0)" ::: "memory");

  // ---- epilogue (operand-swapped layout):
  //   row = m0 + wr*128 + m*16 + (lane&15)
  //   col = n0 + wc*64 + n*16 + (lane>>4)*4 + i
  const int r0 = m0 + wr * 128 + (lane & 15);
  const int cb = n0 + wc * 64 + (lane >> 4) * 4;
  if constexpr (OUT_BF16_BIAS) {
    uint16_t* C = (uint16_t*)Cout;
#pragma unroll
    for (int n = 0; n < 4; ++n) {
      const int col = cb + n * 16;
      const float4 bv = *reinterpret_cast<const float4*>(&bias[col]);
#pragma unroll
      for (int m = 0; m < 8; ++m) {
        const int row = r0 + m * 16;
        ushort4 o;
        o.x = f32_to_bf16(acc[m][n][0] + bv.x);
        o.y = f32_to_bf16(acc[m][n][1] + bv.y);
        o.z = f32_to_bf16(acc[m][n][2] + bv.z);
        o.w = f32_to_bf16(acc[m][n][3] + bv.w);
        *reinterpret_cast<ushort4*>(&C[(size_t)row * N + col]) = o;
      }
    }
  } else {
    float* C = (float*)Cout;
#pragma unroll
    for (int n = 0; n < 4; ++n) {
      const int col = cb + n * 16;
#pragma unroll
      for (int m = 0; m < 8; ++m) {
        const int row = r0 + m * 16;
        float4 o;
        o.x = acc[m][n][0]; o.y = acc[m][n][1];
        o.z = acc[m][n][2]; o.w = acc[m][n][3];
        *reinterpret_cast<float4*>(&C[(size_t)row * N + col]) = o;
      }
    }
  }
}

// ---------------- scan: h_t = a_t*h_{t-1} + v_t,  h_0 = 0.5 ----------------
__device__ __forceinline__ void gate_val(float kz, float hx, float& a, float& v) {
  float ek = __expf(-fabsf(kz));
  float r  = 1.0f / (1.0f + ek);
  float z  = (kz >= 0.0f) ? r : ek * r;   // sigmoid(k)
  a        = (kz >= 0.0f) ? ek * r : r;   // 1 - sigmoid(k)
  float g;
  if (hx >= 0.0f) {
    g = hx + 0.5f;
  } else {
    float eh = __expf(hx);
    g = eh / (1.0f + eh);
  }
  v = z * g;
}

__global__ __launch_bounds__(256) void scan_pass1(
    const uint16_t* __restrict__ proj, float* __restrict__ Ac,
    float* __restrict__ Vc, int T, int E, int CH, int L) {
  const int e = blockIdx.x * 256 + threadIdx.x;
  const int c = blockIdx.y;
  const int b = blockIdx.z;
  const int N1 = 2 * E;
  const uint16_t* p = proj + (size_t)(b * T + c * L) * N1 + e;
  float A = 1.0f, V = 0.0f;
  for (int t = 0; t < L; ++t) {
    float kz = bf16_to_f32(p[0]);
    float hx = bf16_to_f32(p[E]);
    float a, v; gate_val(kz, hx, a, v);
    A *= a;
    V = a * V + v;
    p += N1;
  }
  const size_t idx = ((size_t)(b * CH + c)) * E + e;
  Ac[idx] = A; Vc[idx] = V;
}

__global__ __launch_bounds__(256) void scan_pass2(
    const float* __restrict__ Ac, const float* __restrict__ Vc,
    float* __restrict__ hstart, int E, int CH) {
  const int e = blockIdx.x * 256 + threadIdx.x;
  const int b = blockIdx.y;
  float h = 0.5f;
  for (int c = 0; c < CH; ++c) {
    const size_t idx = ((size_t)(b * CH + c)) * E + e;
    hstart[idx] = h;
    h = Ac[idx] * h + Vc[idx];
  }
}

__global__ __launch_bounds__(256) void scan_pass3(
    const uint16_t* __restrict__ proj, const float* __restrict__ hstart,
    uint16_t* __restrict__ hout, int T, int E, int CH, int L) {
  const int e = blockIdx.x * 256 + threadIdx.x;
  const int c = blockIdx.y;
  const int b = blockIdx.z;
  const int N1 = 2 * E;
  const uint16_t* p = proj + (size_t)(b * T + c * L) * N1 + e;
  uint16_t* o = hout + (size_t)(b * T + c * L) * E + e;
  float h = hstart[((size_t)(b * CH + c)) * E + e];
  for (int t = 0; t < L; ++t) {
    float kz = bf16_to_f32(p[0]);
    float hx = bf16_to_f32(p[E]);
    float a, v; gate_val(kz, hx, a, v);
    h = a * h + v;
    *o = f32_to_bf16(h);
    p += N1; o += E;
  }
}

extern "C" void kernel_launch(void* const* d_in, const int* in_sizes, int n_in,
                              void* d_out, int out_size, void* d_ws, size_t ws_size,
                              hipStream_t stream) {
  const float* x   = (const float*)d_in[0];
  const float* W_f = (const float*)d_in[1];
  const float* b_f = (const float*)d_in[2];
  const float* W_d = (const float*)d_in[3];
  const int Bb = 4, T = 4096, D = 1024, E = 1536;
  const int M = Bb * T;        // 16384
  const int N1 = 2 * E;        // 3072
  const int CH = 64, L = T / CH;

  char* w = (char*)d_ws;
  uint16_t* x_bf  = (uint16_t*)w; w += (size_t)M * D * 2;
  uint16_t* Wf_bf = (uint16_t*)w; w += (size_t)N1 * D * 2;
  uint16_t* Wd_bf = (uint16_t*)w; w += (size_t)D * E * 2;
  uint16_t* proj  = (uint16_t*)w; w += (size_t)M * N1 * 2;
  uint16_t* h_bf  = (uint16_t*)w; w += (size_t)M * E * 2;
  float* Ac     = (float*)w; w += (size_t)Bb * CH * E * 4;
  float* Vc     = (float*)w; w += (size_t)Bb * CH * E * 4;
  float* hstart = (float*)w; w += (size_t)Bb * CH * E * 4;

  cast_f32_bf16<<<M * D / 4 / 256, 256, 0, stream>>>(x, x_bf, M * D / 4);
  cast_f32_bf16<<<N1 * D / 4 / 256, 256, 0, stream>>>(W_f, Wf_bf, N1 * D / 4);
  cast_f32_bf16<<<D * E / 4 / 256, 256, 0, stream>>>(W_d, Wd_bf, D * E / 4);

  // proj = x @ W_f^T + b_f (bf16 out);  grid 768
  gemm256<1><<<(M / 256) * (N1 / 256), 512, 0, stream>>>(
      x_bf, Wf_bf, b_f, proj, M, N1, D);

  scan_pass1<<<dim3(E / 256, CH, Bb), 256, 0, stream>>>(proj, Ac, Vc, T, E, CH, L);
  scan_pass2<<<dim3(E / 256, Bb), 256, 0, stream>>>(Ac, Vc, hstart, E, CH);
  scan_pass3<<<dim3(E / 256, CH, Bb), 256, 0, stream>>>(proj, hstart, h_bf, T, E, CH, L);

  // out = h @ W_down^T (fp32 out);  grid 256
  gemm256<0><<<(M / 256) * (D / 256), 512, 0, stream>>>(
      h_bf, Wd_bf, nullptr, d_out, M, D, E);
}

// Round 6
// 282.971 us; speedup vs baseline: 1.0389x; 1.0066x over previous
//
#include <hip/hip_runtime.h>
#include <hip/hip_bf16.h>
#include <stdint.h>

// minGRU: proj = x@W_f^T + b_f (bf16 GEMM) -> chunked linear scan -> out = h@W_down^T
// B=4 T=4096 D=1024 E=1536.
// GEMM: 256x256 tile, BK=32, 8 waves, 4-deep LDS ring, counted vmcnt(8),
// 2 phases/iter with {reads -> raw barrier -> lgkmcnt(0) AFTER -> 16-MFMA},
// T2 XOR swizzle, operand-swapped MFMA epilogue, L2-patch block map.

typedef __bf16 bf16x8 __attribute__((ext_vector_type(8)));
typedef float  f32x4  __attribute__((ext_vector_type(4)));

__device__ __forceinline__ uint16_t f32_to_bf16(float f) {
  union { float f; uint32_t u; } v; v.f = f;
  uint32_t r = (v.u + 0x7FFFu + ((v.u >> 16) & 1u)) >> 16;  // RNE
  return (uint16_t)r;
}
__device__ __forceinline__ float bf16_to_f32(uint16_t u) {
  union { uint32_t u; float f; } v; v.u = ((uint32_t)u) << 16;
  return v.f;
}

__device__ __forceinline__ void gload_lds16(const uint16_t* g, uint16_t* l) {
  __builtin_amdgcn_global_load_lds(
      (__attribute__((address_space(1))) void*)(g),
      (__attribute__((address_space(3))) void*)(l), 16, 0, 0);
}

// ---------------- cast fp32 -> bf16, x4 vectorized ----------------
__global__ __launch_bounds__(256) void cast_f32_bf16(
    const float* __restrict__ in, uint16_t* __restrict__ out, int n4) {
  int i = blockIdx.x * blockDim.x + threadIdx.x;
  if (i >= n4) return;
  float4 v = reinterpret_cast<const float4*>(in)[i];
  ushort4 o;
  o.x = f32_to_bf16(v.x); o.y = f32_to_bf16(v.y);
  o.z = f32_to_bf16(v.z); o.w = f32_to_bf16(v.w);
  reinterpret_cast<ushort4*>(out)[i] = o;
}

// ---------------- bf16 GEMM, C = A(M,K) * Bt(N,K)^T, 256^2 pipelined --------
// Requires M == 16384 (64 m-tiles), N % 1024 == 0.
// Iter u: fence{vmcnt(8); s_barrier};
//  ph0: rd A0-3,B0-3 (8x b128); gload Ag0,Ag1 (tile u+3);
//       sched_bar; s_barrier; lgkmcnt(0); sched_bar; prio1; 16 MFMA m0-3; prio0
//  ph1: rd A4-7 (4x b128); gload Bg0,Bg1;
//       sched_bar; s_barrier; lgkmcnt(0); sched_bar; prio1; 16 MFMA m4-7; prio0
// Intra-iter barriers are pure scheduling (reads hit tile u, writes tile u+3:
// disjoint buffers) -> no drains needed. WAR: stage targets buf[(u-1)&3]; all
// waves' reads of it drained (their ph1 lgkmcnt(0)) before fence barrier.
// RAW: vmcnt(8) leaves tiles u+1,u+2 (8 loads/wave) in flight; tile u landed.
template <int OUT_BF16_BIAS>
__global__ __launch_bounds__(512, 2) void gemm256(
    const uint16_t* __restrict__ A, const uint16_t* __restrict__ Bt,
    const float* __restrict__ bias, void* __restrict__ Cout,
    int M, int N, int K) {
  __shared__ alignas(16) uint16_t lds[4 * 16384];  // 128 KB

  const int tid  = threadIdx.x;
  const int wave = tid >> 6;
  const int lane = tid & 63;
  const int wr = wave >> 2;      // 0..1  (rows, 128 each)
  const int wc = wave & 3;       // 0..3  (cols, 64 each)

  // L2-fitting patch map (2m x 4n tiles per patch; XCD x = bid&7)
  const int bid = (int)blockIdx.x;
  const int xq  = bid & 7;
  const int j   = bid >> 3;
  const int pi  = xq + ((j >> 3) << 3);
  const int q   = j & 7;
  const int mt  = ((pi & 31) << 1) + (q >> 2);
  const int nt  = ((pi >> 5) << 2) + (q & 3);
  const int m0  = mt << 8;
  const int n0  = nt << 8;

  const int NT = K >> 5;  // BK = 32

  // staging: linear LDS dest, inverse-swizzled global source
  const int srow = wave * 16 + (lane >> 2);
  const int skg  = (lane & 3) ^ ((lane >> 3) & 3);
  const uint16_t* Ag0 = A  + (size_t)(m0 + srow) * K + skg * 8;
  const uint16_t* Ag1 = A  + (size_t)(m0 + 128 + srow) * K + skg * 8;
  const uint16_t* Bg0 = Bt + (size_t)(n0 + srow) * K + skg * 8;
  const uint16_t* Bg1 = Bt + (size_t)(n0 + 128 + srow) * K + skg * 8;
  const int sdw = wave * 512;  // elems

  // swizzled read bases (elems): row*32 + (kg ^ ((row>>1)&3))*8
  const int kgq = (lane >> 4) ^ ((lane >> 1) & 3);
  const int rA = (wr * 128 + (lane & 15)) * 32 + kgq * 8;
  const int rB = (wc * 64  + (lane & 15)) * 32 + kgq * 8;

  f32x4 acc[8][4] = {};

  // prologue: stage tiles 0,1,2
#pragma unroll
  for (int tt = 0; tt < 3; ++tt) {
    uint16_t* sb = &lds[tt * 16384];
    gload_lds16(Ag0 + tt * 32, sb + sdw);
    gload_lds16(Ag1 + tt * 32, sb + 4096 + sdw);
    gload_lds16(Bg0 + tt * 32, sb + 8192 + sdw);
    gload_lds16(Bg1 + tt * 32, sb + 12288 + sdw);
  }

  for (int u = 0; u < NT; ++u) {
    const uint16_t* Ab = &lds[(u & 3) * 16384 + rA];
    const uint16_t* Bb = &lds[(u & 3) * 16384 + 8192 + rB];
    const int us = (u + 3 < NT) ? (u + 3) : (NT - 1);  // clamp: uniform vmcnt
    uint16_t* sb = &lds[((u + 3) & 3) * 16384];
    const size_t kofs = (size_t)us * 32;

    asm volatile("s_waitcnt vmcnt(8)" ::: "memory");
    __builtin_amdgcn_s_barrier();

    bf16x8 af0[4], af1[4], bfr[4];
    // ---- ph0: issue reads, then barrier, drain AFTER barrier ----
#pragma unroll
    for (int m = 0; m < 4; ++m) af0[m] = *reinterpret_cast<const bf16x8*>(Ab + m * 512);
#pragma unroll
    for (int n = 0; n < 4; ++n) bfr[n] = *reinterpret_cast<const bf16x8*>(Bb + n * 512);
    gload_lds16(Ag0 + kofs, sb + sdw);
    gload_lds16(Ag1 + kofs, sb + 4096 + sdw);
    __builtin_amdgcn_sched_barrier(0);
    __builtin_amdgcn_s_barrier();
    asm volatile("s_waitcnt lgkmcnt(0)" ::: "memory");
    __builtin_amdgcn_sched_barrier(0);
    __builtin_amdgcn_s_setprio(1);
#pragma unroll
    for (int m = 0; m < 4; ++m)
#pragma unroll
      for (int n = 0; n < 4; ++n)
        acc[m][n] = __builtin_amdgcn_mfma_f32_16x16x32_bf16(bfr[n], af0[m], acc[m][n], 0, 0, 0);
    __builtin_amdgcn_s_setprio(0);
    __builtin_amdgcn_sched_barrier(0);

    // ---- ph1 ----
#pragma unroll
    for (int m = 0; m < 4; ++m) af1[m] = *reinterpret_cast<const bf16x8*>(Ab + (m + 4) * 512);
    gload_lds16(Bg0 + kofs, sb + 8192 + sdw);
    gload_lds16(Bg1 + kofs, sb + 12288 + sdw);
    __builtin_amdgcn_sched_barrier(0);
    __builtin_amdgcn_s_barrier();
    asm volatile("s_waitcnt lgkmcnt(0)" ::: "memory");
    __builtin_amdgcn_sched_barrier(0);
    __builtin_amdgcn_s_setprio(1);
#pragma unroll
    for (int m = 0; m < 4; ++m)
#pragma unroll
      for (int n = 0; n < 4; ++n)
        acc[m + 4][n] = __builtin_amdgcn_mfma_f32_16x16x32_bf16(bfr[n], af1[m], acc[m + 4][n], 0, 0, 0);
    __builtin_amdgcn_s_setprio(0);
    __builtin_amdgcn_sched_barrier(0);
  }
  asm volatile("s_waitcnt vmcnt(0)" ::: "memory");

  // ---- epilogue (operand-swapped layout):
  //   row = m0 + wr*128 + m*16 + (lane&15)
  //   col = n0 + wc*64 + n*16 + (lane>>4)*4 + i
  const int r0 = m0 + wr * 128 + (lane & 15);
  const int cb = n0 + wc * 64 + (lane >> 4) * 4;
  if constexpr (OUT_BF16_BIAS) {
    uint16_t* C = (uint16_t*)Cout;
#pragma unroll
    for (int m = 0; m < 8; ++m) {
      const int row = r0 + m * 16;
#pragma unroll
      for (int n = 0; n < 4; ++n) {   // n inner: 4 stores per row back-to-back
        const int col = cb + n * 16;
        ushort4 o;
        o.x = f32_to_bf16(acc[m][n][0] + bias[col + 0]);
        o.y = f32_to_bf16(acc[m][n][1] + bias[col + 1]);
        o.z = f32_to_bf16(acc[m][n][2] + bias[col + 2]);
        o.w = f32_to_bf16(acc[m][n][3] + bias[col + 3]);
        *reinterpret_cast<ushort4*>(&C[(size_t)row * N + col]) = o;
      }
    }
  } else {
    float* C = (float*)Cout;
#pragma unroll
    for (int m = 0; m < 8; ++m) {
      const int row = r0 + m * 16;
#pragma unroll
      for (int n = 0; n < 4; ++n) {
        const int col = cb + n * 16;
        float4 o;
        o.x = acc[m][n][0]; o.y = acc[m][n][1];
        o.z = acc[m][n][2]; o.w = acc[m][n][3];
        *reinterpret_cast<float4*>(&C[(size_t)row * N + col]) = o;
      }
    }
  }
}

// ---------------- scan: h_t = a_t*h_{t-1} + v_t,  h_0 = 0.5 ----------------
__device__ __forceinline__ void gate_val(float kz, float hx, float& a, float& v) {
  float ek = __expf(-fabsf(kz));
  float r  = 1.0f / (1.0f + ek);
  float z  = (kz >= 0.0f) ? r : ek * r;   // sigmoid(k)
  a        = (kz >= 0.0f) ? ek * r : r;   // 1 - sigmoid(k)
  float g;
  if (hx >= 0.0f) {
    g = hx + 0.5f;
  } else {
    float eh = __expf(hx);
    g = eh / (1.0f + eh);
  }
  v = z * g;
}

__global__ __launch_bounds__(256) void scan_pass1(
    const uint16_t* __restrict__ proj, float* __restrict__ Ac,
    float* __restrict__ Vc, int T, int E, int CH, int L) {
  const int e = blockIdx.x * 256 + threadIdx.x;
  const int c = blockIdx.y;
  const int b = blockIdx.z;
  const int N1 = 2 * E;
  const uint16_t* p = proj + (size_t)(b * T + c * L) * N1 + e;
  float A = 1.0f, V = 0.0f;
  for (int t = 0; t < L; ++t) {
    float kz = bf16_to_f32(p[0]);
    float hx = bf16_to_f32(p[E]);
    float a, v; gate_val(kz, hx, a, v);
    A *= a;
    V = a * V + v;
    p += N1;
  }
  const size_t idx = ((size_t)(b * CH + c)) * E + e;
  Ac[idx] = A; Vc[idx] = V;
}

__global__ __launch_bounds__(256) void scan_pass2(
    const float* __restrict__ Ac, const float* __restrict__ Vc,
    float* __restrict__ hstart, int E, int CH) {
  const int e = blockIdx.x * 256 + threadIdx.x;
  const int b = blockIdx.y;
  float h = 0.5f;
  for (int c = 0; c < CH; ++c) {
    const size_t idx = ((size_t)(b * CH + c)) * E + e;
    hstart[idx] = h;
    h = Ac[idx] * h + Vc[idx];
  }
}

__global__ __launch_bounds__(256) void scan_pass3(
    const uint16_t* __restrict__ proj, const float* __restrict__ hstart,
    uint16_t* __restrict__ hout, int T, int E, int CH, int L) {
  const int e = blockIdx.x * 256 + threadIdx.x;
  const int c = blockIdx.y;
  const int b = blockIdx.z;
  const int N1 = 2 * E;
  const uint16_t* p = proj + (size_t)(b * T + c * L) * N1 + e;
  uint16_t* o = hout + (size_t)(b * T + c * L) * E + e;
  float h = hstart[((size_t)(b * CH + c)) * E + e];
  for (int t = 0; t < L; ++t) {
    float kz = bf16_to_f32(p[0]);
    float hx = bf16_to_f32(p[E]);
    float a, v; gate_val(kz, hx, a, v);
    h = a * h + v;
    *o = f32_to_bf16(h);
    p += N1; o += E;
  }
}

extern "C" void kernel_launch(void* const* d_in, const int* in_sizes, int n_in,
                              void* d_out, int out_size, void* d_ws, size_t ws_size,
                              hipStream_t stream) {
  const float* x   = (const float*)d_in[0];
  const float* W_f = (const float*)d_in[1];
  const float* b_f = (const float*)d_in[2];
  const float* W_d = (const float*)d_in[3];
  const int Bb = 4, T = 4096, D = 1024, E = 1536;
  const int M = Bb * T;        // 16384
  const int N1 = 2 * E;        // 3072
  const int CH = 64, L = T / CH;

  char* w = (char*)d_ws;
  uint16_t* x_bf  = (uint16_t*)w; w += (size_t)M * D * 2;
  uint16_t* Wf_bf = (uint16_t*)w; w += (size_t)N1 * D * 2;
  uint16_t* Wd_bf = (uint16_t*)w; w += (size_t)D * E * 2;
  uint16_t* proj  = (uint16_t*)w; w += (size_t)M * N1 * 2;
  uint16_t* h_bf  = (uint16_t*)w; w += (size_t)M * E * 2;
  float* Ac     = (float*)w; w += (size_t)Bb * CH * E * 4;
  float* Vc     = (float*)w; w += (size_t)Bb * CH * E * 4;
  float* hstart = (float*)w; w += (size_t)Bb * CH * E * 4;

  cast_f32_bf16<<<M * D / 4 / 256, 256, 0, stream>>>(x, x_bf, M * D / 4);
  cast_f32_bf16<<<N1 * D / 4 / 256, 256, 0, stream>>>(W_f, Wf_bf, N1 * D / 4);
  cast_f32_bf16<<<D * E / 4 / 256, 256, 0, stream>>>(W_d, Wd_bf, D * E / 4);

  // proj = x @ W_f^T + b_f (bf16 out);  grid 768
  gemm256<1><<<(M / 256) * (N1 / 256), 512, 0, stream>>>(
      x_bf, Wf_bf, b_f, proj, M, N1, D);

  scan_pass1<<<dim3(E / 256, CH, Bb), 256, 0, stream>>>(proj, Ac, Vc, T, E, CH, L);
  scan_pass2<<<dim3(E / 256, Bb), 256, 0, stream>>>(Ac, Vc, hstart, E, CH);
  scan_pass3<<<dim3(E / 256, CH, Bb), 256, 0, stream>>>(proj, hstart, h_bf, T, E, CH, L);

  // out = h @ W_down^T (fp32 out);  grid 256
  gemm256<0><<<(M / 256) * (D / 256), 512, 0, stream>>>(
      h_bf, Wd_bf, nullptr, d_out, M, D, E);
}